// Round 13
// baseline (77.894 us; speedup 1.0000x reference)
//
#include <hip/hip_runtime.h>

typedef float v2f __attribute__((ext_vector_type(2)));
#define FMA2(a,b,c) __builtin_elementwise_fma((a),(b),(c))
#define MAX2(a,b)   __builtin_elementwise_max((a),(b))

#define SPOS 2500
#define SSTRIDE 2560                 // padded column count for LC rows
#define NSLICE 8
#define NREP 4                       // k1 work replication (diagnostic)
#define PART_REGION (256 * 8 * NSLICE * 16)
// ws layout (floats): LC float4[32][SSTRIDE] | A[64] | WoT[4096] | part[NREP regions]
#define WS_A_OFF    (32 * SSTRIDE * 4)
#define WS_WOT_OFF  (WS_A_OFF + 64)
#define WS_PART_OFF (WS_WOT_OFF + 4096)
#define SCL (0.35355339059327373f * 1.4426950408889634f)   // 1/sqrt(8) * log2(e)

// Kernel A: LC precompute (coalesced via LDS transpose), A[64], WoT.
// sc[h][t] = A*x^2 + L*x + C in exp2 domain; L,C shared by all 256 batches.
__global__ __launch_bounds__(256) void attn_pool_pre(
    const float* __restrict__ wq, const float* __restrict__ bq,
    const float* __restrict__ wk, const float* __restrict__ bk,
    const float* __restrict__ pe, const float* __restrict__ Wo,
    float* __restrict__ ws)
{
    const int bx  = blockIdx.x;
    const int tid = threadIdx.x;

    if (bx < 79) {
        __shared__ float4 lds[32][33];       // [j2 row][s_local], +1 pad
        const int s0 = bx * 32;
        const int sl = tid >> 3;             // s_local 0..31
        const int s  = s0 + sl;
        const int h  = tid & 7;

        if (s < SPOS) {
            float per[64];
            const float4* p4 = (const float4*)(pe + (size_t)s * 64);
            #pragma unroll
            for (int j = 0; j < 16; ++j) {
                const float4 t = p4[j];
                per[4*j] = t.x; per[4*j+1] = t.y; per[4*j+2] = t.z; per[4*j+3] = t.w;
            }

            float eq[8];
            #pragma unroll
            for (int d = 0; d < 8; ++d) eq[d] = bq[h*8+d] + per[h*8+d];

            #pragma unroll
            for (int t = 0; t < 8; t += 2) {
                float l0 = 0.f, c0 = 0.f, l1 = 0.f, c1 = 0.f;
                #pragma unroll
                for (int d = 0; d < 8; ++d) {
                    const float ek0 = bk[t*8+d]     + per[t*8+d];
                    const float ek1 = bk[(t+1)*8+d] + per[(t+1)*8+d];
                    l0 = fmaf(wq[h*8+d], ek0,   l0);
                    l0 = fmaf(wk[t*8+d], eq[d], l0);
                    c0 = fmaf(eq[d], ek0, c0);
                    l1 = fmaf(wq[h*8+d], ek1,        l1);
                    l1 = fmaf(wk[(t+1)*8+d], eq[d],  l1);
                    c1 = fmaf(eq[d], ek1, c1);
                }
                lds[h*4 + (t>>1)][sl] =
                    make_float4(l0 * SCL, l1 * SCL, c0 * SCL, c1 * SCL);
            }
        }
        __syncthreads();

        float4* lc4 = (float4*)ws;
        #pragma unroll
        for (int k = 0; k < 4; ++k) {
            const int flat = k * 256 + tid;
            const int row = flat >> 5, col = flat & 31;
            if (s0 + col < SPOS)
                lc4[(size_t)row * SSTRIDE + s0 + col] = lds[row][col];
        }
    } else if (bx == 79) {
        if (tid < 64) {
            const int hh = tid >> 3, tt = tid & 7;
            float a = 0.f;
            #pragma unroll
            for (int d = 0; d < 8; ++d) a = fmaf(wq[hh*8+d], wk[tt*8+d], a);
            ws[WS_A_OFF + tid] = a * SCL;
        }
    } else {
        const int i = (bx - 80) * 256 + tid;   // 0..4095 ; i = j*64 + f
        const int j = i >> 6, f = i & 63;
        ws[WS_WOT_OFF + i] = Wo[(size_t)f * 64 + j];   // WoT[j][f]
    }
}

// One batch's softmax+accumulate, all state in named scalars (no private
// arrays -> no scratch risk per rule #20).
static __device__ __forceinline__ void proc_batch(
    float x,
    float4 q0, float4 q1, float4 q2, float4 q3,
    float a0, float a1, float a2, float a3,
    float a4, float a5, float a6, float a7,
    v2f& A0, v2f& A1, v2f& A2, v2f& A3,
    v2f& B0, v2f& B1, v2f& B2, v2f& B3)
{
    const v2f xx = {x, x};
    v2f e0, e1, e2, e3;
    {
        const float u0 = fmaf(x, a0, q0.x), u1 = fmaf(x, a1, q0.y);
        const v2f uu = {u0, u1}; const v2f cv = {q0.z, q0.w};
        e0 = FMA2(uu, xx, cv);
    }
    {
        const float u0 = fmaf(x, a2, q1.x), u1 = fmaf(x, a3, q1.y);
        const v2f uu = {u0, u1}; const v2f cv = {q1.z, q1.w};
        e1 = FMA2(uu, xx, cv);
    }
    {
        const float u0 = fmaf(x, a4, q2.x), u1 = fmaf(x, a5, q2.y);
        const v2f uu = {u0, u1}; const v2f cv = {q2.z, q2.w};
        e2 = FMA2(uu, xx, cv);
    }
    {
        const float u0 = fmaf(x, a6, q3.x), u1 = fmaf(x, a7, q3.y);
        const v2f uu = {u0, u1}; const v2f cv = {q3.z, q3.w};
        e3 = FMA2(uu, xx, cv);
    }
    const v2f m2 = MAX2(MAX2(e0, e1), MAX2(e2, e3));
    const float m = fmaxf(m2.x, m2.y);
    const v2f ms = {m, m};
    e0 -= ms; e1 -= ms; e2 -= ms; e3 -= ms;
    e0.x = exp2f(e0.x); e0.y = exp2f(e0.y);
    e1.x = exp2f(e1.x); e1.y = exp2f(e1.y);
    e2.x = exp2f(e2.x); e2.y = exp2f(e2.y);
    e3.x = exp2f(e3.x); e3.y = exp2f(e3.y);
    const v2f den2 = (e0 + e1) + (e2 + e3);
    const float inv  = __builtin_amdgcn_rcpf(den2.x + den2.y);
    const float xinv = x * inv;
    const v2f vi = {inv, inv}, vx = {xinv, xinv};
    A0 = FMA2(vi, e0, A0); A1 = FMA2(vi, e1, A1);
    A2 = FMA2(vi, e2, A2); A3 = FMA2(vi, e3, A3);
    B0 = FMA2(vx, e0, B0); B1 = FMA2(vx, e1, B1);
    B2 = FMA2(vx, e2, B2); B3 = FMA2(vx, e3, B3);
}

// Kernel B: wave = (head, 2-batch group, slice); lane = position. LC float4s
// register-shared across 2 batches; next iteration's LC+sim prefetched.
// DIAGNOSTIC: NREP replicas of the whole job in one dispatch (rep = bx>>11),
// writing disjoint part regions, so the dispatch is long enough to surface in
// the profile top-5 with true VGPR/VALUBusy/Occupancy.
__global__ __launch_bounds__(256) void attn_pool_k1(
    const float* __restrict__ sim,
    const float* __restrict__ ws, float* __restrict__ part)
{
    const int bxr  = blockIdx.x;            // 0..8191
    const int rep  = bxr >> 11;             // 0..3
    const int bx   = bxr & 2047;
    const int bg   = bx >> 4;               // 0..127: batches bg*2, bg*2+1
    const int sl   = (bx >> 1) & 7;         // slice 0..7
    const int hq   = bx & 1;
    const int wave = threadIdx.x >> 6;
    const int lane = threadIdx.x & 63;
    const int h    = hq * 4 + wave;         // head 0..7

    float* pout = part + (size_t)rep * PART_REGION;

    const int s_begin = (sl * SPOS) >> 3;
    const int s_end   = ((sl + 1) * SPOS) >> 3;   // 312/313 positions

    const float4* lch = (const float4*)ws + (size_t)(h * 4) * SSTRIDE;

    // A row for this head -> 8 SGPRs (readfirstlane), named scalars
    const float a0 = __int_as_float(__builtin_amdgcn_readfirstlane(__float_as_int(ws[WS_A_OFF + h*8 + 0])));
    const float a1 = __int_as_float(__builtin_amdgcn_readfirstlane(__float_as_int(ws[WS_A_OFF + h*8 + 1])));
    const float a2 = __int_as_float(__builtin_amdgcn_readfirstlane(__float_as_int(ws[WS_A_OFF + h*8 + 2])));
    const float a3 = __int_as_float(__builtin_amdgcn_readfirstlane(__float_as_int(ws[WS_A_OFF + h*8 + 3])));
    const float a4 = __int_as_float(__builtin_amdgcn_readfirstlane(__float_as_int(ws[WS_A_OFF + h*8 + 4])));
    const float a5 = __int_as_float(__builtin_amdgcn_readfirstlane(__float_as_int(ws[WS_A_OFF + h*8 + 5])));
    const float a6 = __int_as_float(__builtin_amdgcn_readfirstlane(__float_as_int(ws[WS_A_OFF + h*8 + 6])));
    const float a7 = __int_as_float(__builtin_amdgcn_readfirstlane(__float_as_int(ws[WS_A_OFF + h*8 + 7])));

    // Accumulators: named (16 v2f = 32 VGPR)
    v2f P0a0 = (v2f)(0.f), P0a1 = (v2f)(0.f), P0a2 = (v2f)(0.f), P0a3 = (v2f)(0.f);
    v2f P0b0 = (v2f)(0.f), P0b1 = (v2f)(0.f), P0b2 = (v2f)(0.f), P0b3 = (v2f)(0.f);
    v2f P1a0 = (v2f)(0.f), P1a1 = (v2f)(0.f), P1a2 = (v2f)(0.f), P1a3 = (v2f)(0.f);
    v2f P1b0 = (v2f)(0.f), P1b1 = (v2f)(0.f), P1b2 = (v2f)(0.f), P1b3 = (v2f)(0.f);

    const float* simb = sim + (size_t)(bg * 2) * SPOS;

    // Prefetch iteration 0 (named)
    int  s  = s_begin + lane;
    bool v  = s < s_end;
    int  so = v ? s : s_begin;
    float4 q0 = lch[0 * SSTRIDE + so];
    float4 q1 = lch[1 * SSTRIDE + so];
    float4 q2 = lch[2 * SSTRIDE + so];
    float4 q3 = lch[3 * SSTRIDE + so];
    float xb0 = simb[so];
    float xb1 = simb[SPOS + so];

    #pragma unroll 1
    for (int it = 0; it < 5; ++it) {
        float4 n0, n1, n2, n3;
        float xn0, xn1;
        if (it < 4) {
            const int sn  = s + 64;
            const int son = (sn < s_end) ? sn : s_begin;
            n0 = lch[0 * SSTRIDE + son];
            n1 = lch[1 * SSTRIDE + son];
            n2 = lch[2 * SSTRIDE + son];
            n3 = lch[3 * SSTRIDE + son];
            xn0 = simb[son];
            xn1 = simb[SPOS + son];
        }

        if (v) {
            proc_batch(xb0, q0, q1, q2, q3, a0,a1,a2,a3,a4,a5,a6,a7,
                       P0a0, P0a1, P0a2, P0a3, P1a0, P1a1, P1a2, P1a3);
            proc_batch(xb1, q0, q1, q2, q3, a0,a1,a2,a3,a4,a5,a6,a7,
                       P0b0, P0b1, P0b2, P0b3, P1b0, P1b1, P1b2, P1b3);
        }

        s += 64;
        v = s < s_end;
        q0 = n0; q1 = n1; q2 = n2; q3 = n3;
        xb0 = xn0; xb1 = xn1;
    }

    // Flatten to av[32] (all literal indices after unroll):
    // av[nb*16 + t] = P0[nb][t], av[nb*16 + 8 + t] = P1[nb][t]
    float av[32];
    av[ 0] = P0a0.x; av[ 1] = P0a0.y; av[ 2] = P0a1.x; av[ 3] = P0a1.y;
    av[ 4] = P0a2.x; av[ 5] = P0a2.y; av[ 6] = P0a3.x; av[ 7] = P0a3.y;
    av[ 8] = P1a0.x; av[ 9] = P1a0.y; av[10] = P1a1.x; av[11] = P1a1.y;
    av[12] = P1a2.x; av[13] = P1a2.y; av[14] = P1a3.x; av[15] = P1a3.y;
    av[16] = P0b0.x; av[17] = P0b0.y; av[18] = P0b1.x; av[19] = P0b1.y;
    av[20] = P0b2.x; av[21] = P0b2.y; av[22] = P0b3.x; av[23] = P0b3.y;
    av[24] = P1b0.x; av[25] = P1b0.y; av[26] = P1b1.x; av[27] = P1b1.y;
    av[28] = P1b2.x; av[29] = P1b2.y; av[30] = P1b3.x; av[31] = P1b3.y;

    // Halving-butterfly: 5 stages over lane bits 0..4 (32 -> 1), then xor-32.
    float r16[16];
    #pragma unroll
    for (int i = 0; i < 16; ++i) {
        const bool up = (lane & 1) != 0;
        const float kv   = up ? av[i+16] : av[i];
        const float send = up ? av[i]    : av[i+16];
        r16[i] = kv + __shfl_xor(send, 1, 64);
    }
    float r8[8];
    #pragma unroll
    for (int i = 0; i < 8; ++i) {
        const bool up = (lane & 2) != 0;
        const float kv   = up ? r16[i+8] : r16[i];
        const float send = up ? r16[i]   : r16[i+8];
        r8[i] = kv + __shfl_xor(send, 2, 64);
    }
    float r4[4];
    #pragma unroll
    for (int i = 0; i < 4; ++i) {
        const bool up = (lane & 4) != 0;
        const float kv   = up ? r8[i+4] : r8[i];
        const float send = up ? r8[i]   : r8[i+4];
        r4[i] = kv + __shfl_xor(send, 4, 64);
    }
    float r2[2];
    #pragma unroll
    for (int i = 0; i < 2; ++i) {
        const bool up = (lane & 8) != 0;
        const float kv   = up ? r4[i+2] : r4[i];
        const float send = up ? r4[i]   : r4[i+2];
        r2[i] = kv + __shfl_xor(send, 8, 64);
    }
    float r1;
    {
        const bool up = (lane & 16) != 0;
        const float kv   = up ? r2[1] : r2[0];
        const float send = up ? r2[0] : r2[1];
        r1 = kv + __shfl_xor(send, 16, 64);
    }
    r1 += __shfl_xor(r1, 32, 64);

    // lane l<32 holds av-index f = bitrev5(l)
    if (lane < 32) {
        const int f = ((lane & 1) << 4) | ((lane & 2) << 2) | (lane & 4)
                    | ((lane & 8) >> 2) | ((lane & 16) >> 4);
        const int nb = f >> 4, rem = f & 15;
        pout[(((size_t)(bg*2 + nb) * 8 + h) * NSLICE + sl) * 16 + rem] = r1;
    }
}

// Kernel C: 4 batches per block (one per wave): slice-sum -> wv/bv
// contraction -> mean -> @WoT (coalesced) + bo -> LayerNorm. Reads region 0.
__global__ __launch_bounds__(256) void attn_pool_k2(
    const float* __restrict__ ws,
    const float* __restrict__ wv, const float* __restrict__ bv,
    const float* __restrict__ bo,
    const float* __restrict__ gamma, const float* __restrict__ beta,
    float* __restrict__ out)
{
    const float* part = ws + WS_PART_OFF;
    const float* WoT  = ws + WS_WOT_OFF;
    const int wave = threadIdx.x >> 6;
    const int lane = threadIdx.x & 63;
    const int b = blockIdx.x * 4 + wave;
    const int l = lane;                  // (h,t) for partials, (h,d) for pooled
    const int h = l >> 3, t = l & 7, d = t;

    float p0 = 0.f, p1 = 0.f;            // P0[h][t], P1[h][t]
    #pragma unroll
    for (int sl = 0; sl < NSLICE; ++sl) {
        const size_t base = (((size_t)b * 8 + h) * NSLICE + sl) * 16;
        p0 += part[base + t];
        p1 += part[base + 8 + t];
    }

    // pooled[h,d] = (sum_t P1[h][t]*wv[t,d] + P0[h][t]*bv[t,d]) / S
    float pool = 0.f;
    #pragma unroll
    for (int tt = 0; tt < 8; ++tt) {
        const float P1v = __shfl(p1, h*8 + tt, 64);
        const float P0v = __shfl(p0, h*8 + tt, 64);
        pool = fmaf(P1v, wv[tt*8 + d], pool);
        pool = fmaf(P0v, bv[tt*8 + d], pool);
    }
    pool *= (1.0f / 2500.0f);

    // y = bo + WoT-column dot pooled; 4 independent chains for ILP
    float y0 = 0.f, y1 = 0.f, y2 = 0.f, y3 = 0.f;
    #pragma unroll
    for (int j = 0; j < 64; j += 4) {
        const float pj0 = __shfl(pool, j + 0, 64);
        const float pj1 = __shfl(pool, j + 1, 64);
        const float pj2 = __shfl(pool, j + 2, 64);
        const float pj3 = __shfl(pool, j + 3, 64);
        y0 = fmaf(pj0, WoT[(j + 0) * 64 + l], y0);
        y1 = fmaf(pj1, WoT[(j + 1) * 64 + l], y1);
        y2 = fmaf(pj2, WoT[(j + 2) * 64 + l], y2);
        y3 = fmaf(pj3, WoT[(j + 3) * 64 + l], y3);
    }
    const float y = bo[l] + ((y0 + y1) + (y2 + y3));

    float s1 = y;
    #pragma unroll
    for (int off = 32; off > 0; off >>= 1) s1 += __shfl_xor(s1, off, 64);
    const float mu = s1 * (1.0f / 64.0f);
    const float dlt = y - mu;
    float s2 = dlt * dlt;
    #pragma unroll
    for (int off = 32; off > 0; off >>= 1) s2 += __shfl_xor(s2, off, 64);
    const float var = s2 * (1.0f / 64.0f);

    out[(size_t)b * 64 + l] = dlt * rsqrtf(var + 1e-5f) * gamma[l] + beta[l];
}

extern "C" void kernel_launch(void* const* d_in, const int* in_sizes, int n_in,
                              void* d_out, int out_size, void* d_ws, size_t ws_size,
                              hipStream_t stream) {
    const float* sim   = (const float*)d_in[0];
    const float* wq    = (const float*)d_in[1];
    const float* bq    = (const float*)d_in[2];
    const float* wk    = (const float*)d_in[3];
    const float* bk    = (const float*)d_in[4];
    const float* wv    = (const float*)d_in[5];
    const float* bv    = (const float*)d_in[6];
    const float* pe    = (const float*)d_in[7];
    const float* Wo    = (const float*)d_in[8];
    const float* bo    = (const float*)d_in[9];
    const float* gamma = (const float*)d_in[10];
    const float* beta  = (const float*)d_in[11];
    float* ws   = (float*)d_ws;                 // ~5.5 MB used
    float* part = ws + WS_PART_OFF;
    float* out  = (float*)d_out;

    attn_pool_pre<<<dim3(96),   dim3(256), 0, stream>>>(wq, bq, wk, bk, pe, Wo, ws);
    attn_pool_k1 <<<dim3(8192), dim3(256), 0, stream>>>(sim, ws, part);
    attn_pool_k2 <<<dim3(64),   dim3(256), 0, stream>>>(ws, wv, bv, bo, gamma, beta, out);
}